// Round 16
// baseline (161.791 us; speedup 1.0000x reference)
//
#include <hip/hip_runtime.h>
#include <hip/hip_bf16.h>

#define HEADS 12
#define HD 64
#define PADW 32
#define EMBED 768
#define LSEQ 2048
#define QKV_N (3 * HEADS * HD)   // 2304
#define LPAD (LSEQ + 64)         // 2112

typedef short short8 __attribute__((ext_vector_type(8)));
typedef short short4v __attribute__((ext_vector_type(4)));
typedef float f32x4 __attribute__((ext_vector_type(4)));

// Static scratch, fully overwritten every call (poison-safe).
__device__ short g_xb[LSEQ * EMBED];        // x bf16             [2048][768]
__device__ short g_wqkvT[QKV_N * EMBED];    // w_qkv^T bf16       [2304][768]
__device__ short g_woutT[EMBED * EMBED];    // w_out^T bf16       [768][768]
__device__ short g_qkvb[LSEQ * QKV_N];      // qkv bf16           [2048][2304]
__device__ short g_vT[HEADS * HD * LPAD];   // V^T bf16, 0-padded [768][2112]
__device__ short g_attnb[LSEQ * EMBED];     // attn out bf16      [2048][768]

__device__ __forceinline__ short f2bf(float f) {
  unsigned x = __builtin_bit_cast(unsigned, f);
  x += 0x7fffu + ((x >> 16) & 1u);   // RNE
  return (short)(x >> 16);
}

// ---------------------------------------------------------------------------
// prep (unchanged, verified): A = cast x, B = w_qkv transpose, C = w_out
// transpose, D = zero vT pads. One dispatch, 3864 blocks.
// ---------------------------------------------------------------------------
#define PREP_A 1536              // (2048*768/4)/256
#define PREP_B 1728              // w_qkv: 72 x 24 tiles of 32x32
#define PREP_C 576               // w_out: 24 x 24
#define PREP_D 24                // vT pad zero
#define PREP_TOT (PREP_A + PREP_B + PREP_C + PREP_D)

__global__ __launch_bounds__(256) void prep(
    const float* __restrict__ x, const float* __restrict__ w_qkv,
    const float* __restrict__ w_out, short* __restrict__ xb,
    short* __restrict__ wqkvT, short* __restrict__ woutT,
    short* __restrict__ vT) {
  __shared__ float T[32][33];
  const int b = blockIdx.x, tid = threadIdx.x;
  if (b < PREP_A) {
    int i = b * 256 + tid;
    float4 v = ((const float4*)x)[i];
    short4v o;
    o[0] = f2bf(v.x); o[1] = f2bf(v.y); o[2] = f2bf(v.z); o[3] = f2bf(v.w);
    ((short4v*)xb)[i] = o;
  } else if (b < PREP_A + PREP_B + PREP_C) {
    const float* W; short* WT; int N, bx, by;
    if (b < PREP_A + PREP_B) {
      int t = b - PREP_A; W = w_qkv; WT = wqkvT; N = QKV_N; bx = t % 72; by = t / 72;
    } else {
      int t = b - PREP_A - PREP_B; W = w_out; WT = woutT; N = EMBED; bx = t % 24; by = t / 24;
    }
    const int K = EMBED;
    int tx = tid & 31, ty = tid >> 5;
    int n0 = bx * 32, k0 = by * 32;
#pragma unroll
    for (int p = 0; p < 4; ++p)
      T[ty + p * 8][tx] = W[(size_t)(k0 + ty + p * 8) * N + n0 + tx];
    __syncthreads();
#pragma unroll
    for (int p = 0; p < 4; ++p)
      WT[(size_t)(n0 + ty + p * 8) * K + k0 + tx] = f2bf(T[tx][ty + p * 8]);
  } else {
    int j = (b - PREP_A - PREP_B - PREP_C) * 256 + tid;
    int hd = j >> 3, side = (j >> 2) & 1, off = (j & 3) * 8;
    short8 z = {};
    *(short8*)&vT[(size_t)hd * LPAD + side * 2080 + off] = z;
  }
}

// ---------------------------------------------------------------------------
// ROUND 15 (resubmit — broker timeout): H5 retest — LDS-free K-loop with
// the SCRATCH BUG FIXED. r14 post-mortem: gemm_reg64 showed VGPR_Count=32 —
// impossibly low for 24 in-flight short8 fragments. The Frag struct +
// lambda-byref captures defeated SROA; fragments lived in SCRATCH
// (global-backed), costing ~256B/lane/step of spill traffic -> 58us/gemm,
// MfmaUtil 4.5%. H5 itself (LDS round trip is pure overhead under
// wave-private tiling) was never tested. Fix (rule #20 discipline): NO
// struct, NO lambda, NO arrays — 24 individually named short8 locals
// (3 banks x 8) in fully straight-line macro-unrolled code, scalarized
// acc00..acc11. Same pattern as the verified attn_mfma direct-global
// fragments. Same 12-step depth-2 schedule and identical MFMA order as
// r12/r13 -> bit-identical results.
// ---------------------------------------------------------------------------
#define MFMA_ __builtin_amdgcn_mfma_f32_16x16x32_bf16

#define DECLB(S) short8 a0k0##S, a1k0##S, b0k0##S, b1k0##S, \
                        a0k1##S, a1k1##S, b0k1##S, b1k1##S

#define LOADB(S, j) do { const int o_ = (j) * 64;   \
    a0k0##S = *(const short8*)(pa0 + o_);           \
    a1k0##S = *(const short8*)(pa1 + o_);           \
    b0k0##S = *(const short8*)(pb0 + o_);           \
    b1k0##S = *(const short8*)(pb1 + o_);           \
    a0k1##S = *(const short8*)(pa0 + o_ + 32);      \
    a1k1##S = *(const short8*)(pa1 + o_ + 32);      \
    b0k1##S = *(const short8*)(pb0 + o_ + 32);      \
    b1k1##S = *(const short8*)(pb1 + o_ + 32);      \
  } while (0)

#define COMPB(S) do {                               \
    acc00 = MFMA_(a0k0##S, b0k0##S, acc00, 0, 0, 0);\
    acc01 = MFMA_(a0k0##S, b1k0##S, acc01, 0, 0, 0);\
    acc10 = MFMA_(a1k0##S, b0k0##S, acc10, 0, 0, 0);\
    acc11 = MFMA_(a1k0##S, b1k0##S, acc11, 0, 0, 0);\
    acc00 = MFMA_(a0k1##S, b0k1##S, acc00, 0, 0, 0);\
    acc01 = MFMA_(a0k1##S, b1k1##S, acc01, 0, 0, 0);\
    acc10 = MFMA_(a1k1##S, b0k1##S, acc10, 0, 0, 0);\
    acc11 = MFMA_(a1k1##S, b1k1##S, acc11, 0, 0, 0);\
  } while (0)

#define VT_ST(ACC, ROW0) do { short4v o_;                      \
    o_[0] = f2bf(ACC[0]); o_[1] = f2bf(ACC[1]);                \
    o_[2] = f2bf(ACC[2]); o_[3] = f2bf(ACC[3]);                \
    *(short4v*)&vT[(size_t)(h_ * 64 + d_) * LPAD + PADW + (ROW0)] = o_; \
  } while (0)

template <bool OUT_BF16, bool FUSE_VT>
__global__ __launch_bounds__(256) void gemm_reg64(
    const short* __restrict__ A, const short* __restrict__ Bt,
    const float* __restrict__ bias, void* __restrict__ Cv,
    short* __restrict__ vT, int M, int N, int K) {
  // LDS: wave-private epilogue bounce only.
  constexpr int WEPI = OUT_BF16 ? 32 * 40 : 32 * 36 * 2;   // shorts per wave
  __shared__ __align__(16) short lds_s[4 * WEPI];

  const int tid = threadIdx.x;
  const int wv = tid >> 6, lane = tid & 63;
  const int wm = wv >> 1, wn = wv & 1;
  const int lanelo = lane & 15, quad = lane >> 4;
  const int m0 = blockIdx.y * 64 + wm * 32;      // wave-owned 32 rows
  const int n0 = blockIdx.x * 64 + wn * 32;      // wave-owned 32 cols
  short* wlds = lds_s + wv * WEPI;

  // Per-lane fragment base pointers (quad picks the 16B chunk within 64B).
  const short* pa0 = A + (size_t)(m0 + lanelo) * K + quad * 8;
  const short* pa1 = A + (size_t)(m0 + 16 + lanelo) * K + quad * 8;
  const short* pb0 = Bt + (size_t)(n0 + lanelo) * K + quad * 8;
  const short* pb1 = Bt + (size_t)(n0 + 16 + lanelo) * K + quad * 8;

  f32x4 acc00 = {}, acc01 = {}, acc10 = {}, acc11 = {};

  // K == 768 at both call sites -> 12 steps. 3 named register banks,
  // straight-line: load bank j+2 issued before compute bank j (depth 2).
  DECLB(0); DECLB(1); DECLB(2);
  LOADB(0, 0);
  LOADB(1, 1);
  LOADB(2, 2);  COMPB(0);     // step 0
  LOADB(0, 3);  COMPB(1);     // step 1
  LOADB(1, 4);  COMPB(2);     // step 2
  LOADB(2, 5);  COMPB(0);     // step 3
  LOADB(0, 6);  COMPB(1);     // step 4
  LOADB(1, 7);  COMPB(2);     // step 5
  LOADB(2, 8);  COMPB(0);     // step 6
  LOADB(0, 9);  COMPB(1);     // step 7
  LOADB(1, 10); COMPB(2);     // step 8
  LOADB(2, 11); COMPB(0);     // step 9
  COMPB(1);                   // step 10
  COMPB(2);                   // step 11

  // ---- fused V^T scatter: any 16-col group with c0 % 192 >= 128 is V ----
  if (FUSE_VT) {
    {   // nt = 0 -> acc00 (mt=0), acc10 (mt=1)
      int c0 = n0;
      if ((c0 % 192) >= 128) {
        int h_ = c0 / 192, d_ = (c0 % 192) - 128 + lanelo;
        VT_ST(acc00, m0 + quad * 4);
        VT_ST(acc10, m0 + 16 + quad * 4);
      }
    }
    {   // nt = 1 -> acc01 (mt=0), acc11 (mt=1)
      int c0 = n0 + 16;
      if ((c0 % 192) >= 128) {
        int h_ = c0 / 192, d_ = (c0 % 192) - 128 + lanelo;
        VT_ST(acc01, m0 + quad * 4);
        VT_ST(acc11, m0 + 16 + quad * 4);
      }
    }
  }

  // ---- wave-private coalesced epilogue (no __syncthreads anywhere) ----
  if (OUT_BF16) {
    short* eb = wlds;
#define EPI_B(ACC, MT, NT) do {                                   \
      int rl_ = (MT) * 16 + quad * 4, cl_ = (NT) * 16 + lanelo;   \
      eb[(rl_ + 0) * 40 + cl_] = f2bf(ACC[0]);                    \
      eb[(rl_ + 1) * 40 + cl_] = f2bf(ACC[1]);                    \
      eb[(rl_ + 2) * 40 + cl_] = f2bf(ACC[2]);                    \
      eb[(rl_ + 3) * 40 + cl_] = f2bf(ACC[3]); } while (0)
    EPI_B(acc00, 0, 0); EPI_B(acc01, 0, 1);
    EPI_B(acc10, 1, 0); EPI_B(acc11, 1, 1);
#undef EPI_B
    asm volatile("s_waitcnt lgkmcnt(0)" ::: "memory");
    short* Cc = (short*)Cv;
#pragma unroll
    for (int pass = 0; pass < 2; ++pass) {
      int u = pass * 64 + lane;
      int row = u >> 2, seg = u & 3;             // 32 rows x 4 x short8
      short8 vv = *(const short8*)&eb[row * 40 + seg * 8];
      *(short8*)&Cc[(size_t)(m0 + row) * N + n0 + seg * 8] = vv;
    }
  } else {
    float* fl = (float*)wlds;
#define EPI_F(ACC, MT, NT) do {                                   \
      int rl_ = (MT) * 16 + quad * 4, cl_ = (NT) * 16 + lanelo;   \
      fl[(rl_ + 0) * 36 + cl_] = ACC[0];                          \
      fl[(rl_ + 1) * 36 + cl_] = ACC[1];                          \
      fl[(rl_ + 2) * 36 + cl_] = ACC[2];                          \
      fl[(rl_ + 3) * 36 + cl_] = ACC[3]; } while (0)
    EPI_F(acc00, 0, 0); EPI_F(acc01, 0, 1);
    EPI_F(acc10, 1, 0); EPI_F(acc11, 1, 1);
#undef EPI_F
    asm volatile("s_waitcnt lgkmcnt(0)" ::: "memory");
    float* Cc = (float*)Cv;
#pragma unroll
    for (int pass = 0; pass < 4; ++pass) {
      int u = pass * 64 + lane;
      int row = u >> 3, seg = u & 7;             // 32 rows x 8 x float4
      float4 vv = *(const float4*)&fl[row * 36 + seg * 4];
      float4 bb = *(const float4*)&bias[n0 + seg * 4];
      vv.x += bb.x; vv.y += bb.y; vv.z += bb.z; vv.w += bb.w;
      *(float4*)&Cc[(size_t)(m0 + row) * N + n0 + seg * 4] = vv;
    }
  }
}

// ---------------------------------------------------------------------------
// MFMA windowed attention (unchanged, verified). Block = 64 rows x 1 head;
// 4 waves, 16-row strips; V b-frags prefetched before the softmax phase.
// ---------------------------------------------------------------------------
__global__ __launch_bounds__(256) void attn_mfma(
    const short* __restrict__ qkvb, const short* __restrict__ vT,
    short* __restrict__ attnb) {
  const int blk = blockIdx.x;
  const int h = blk % HEADS;
  const int l0 = (blk / HEADS) * 64;
  const int sb = l0 - PADW;

  const int tid = threadIdx.x;
  const int wv = tid >> 6, lane = tid & 63;
  const int lanelo = lane & 15, quad = lane >> 4;
  const int qoff = h * 192, koff = h * 192 + 64;

  __shared__ __align__(16) short P_lds[64 * 136];

  // Q a-frags
  const short* qp = qkvb + (size_t)(l0 + wv * 16 + lanelo) * QKV_N + qoff;
  short8 aq0 = *(const short8*)(qp + quad * 8);
  short8 aq1 = *(const short8*)(qp + 32 + quad * 8);

  // ---- S = Q.K^T
  f32x4 sacc[8] = {};
#pragma unroll
  for (int nt = 0; nt < 8; ++nt) {
    int gl = sb + nt * 16 + lanelo;
    short8 bk0 = {}, bk1 = {};
    if ((unsigned)gl < (unsigned)LSEQ) {
      const short* kp = qkvb + (size_t)gl * QKV_N + koff;
      bk0 = *(const short8*)(kp + quad * 8);
      bk1 = *(const short8*)(kp + 32 + quad * 8);
    }
    sacc[nt] = __builtin_amdgcn_mfma_f32_16x16x32_bf16(aq0, bk0, sacc[nt], 0, 0, 0);
    sacc[nt] = __builtin_amdgcn_mfma_f32_16x16x32_bf16(aq1, bk1, sacc[nt], 0, 0, 0);
  }

  // ---- V b-frag prefetch (independent of softmax)
  short8 bv[4][4];
#pragma unroll
  for (int ks = 0; ks < 4; ++ks) {
    int lp = l0 + ks * 32 + quad * 8;
#pragma unroll
    for (int nt = 0; nt < 4; ++nt) {
      int d = nt * 16 + lanelo;
      bv[ks][nt] = *(const short8*)&vT[((size_t)h * 64 + d) * LPAD + lp];
    }
  }

  // ---- softmax per row (no max-pass; masked -> exp(-1e30) == 0)
  float rsum[4] = {0.f, 0.f, 0.f, 0.f};
#pragma unroll
  for (int nt = 0; nt < 8; ++nt)
#pragma unroll
    for (int r = 0; r < 4; ++r) {
      int li = wv * 16 + quad * 4 + r;
      int widx = nt * 16 + lanelo - li;
      float s = (widx >= 0 && widx <= 64) ? sacc[nt][r] * 0.125f : -1e30f;
      float p = __expf(s);
      sacc[nt][r] = p;
      rsum[r] += p;
    }
#pragma unroll
  for (int r = 0; r < 4; ++r) {
#pragma unroll
    for (int off = 1; off < 16; off <<= 1)
      rsum[r] += __shfl_xor(rsum[r], off);
    rsum[r] = 1.f / rsum[r];
  }
#pragma unroll
  for (int nt = 0; nt < 8; ++nt)
#pragma unroll
    for (int r = 0; r < 4; ++r) {
      int row = wv * 16 + quad * 4 + r;
      P_lds[row * 136 + nt * 16 + lanelo] = f2bf(sacc[nt][r] * rsum[r]);
    }
  __syncthreads();

  // ---- O = P.V (V already in regs)
  f32x4 oacc[4] = {};
#pragma unroll
  for (int ks = 0; ks < 4; ++ks) {
    short8 ap = *(const short8*)&P_lds[(wv * 16 + lanelo) * 136 + ks * 32 + quad * 8];
#pragma unroll
    for (int nt = 0; nt < 4; ++nt)
      oacc[nt] = __builtin_amdgcn_mfma_f32_16x16x32_bf16(ap, bv[ks][nt], oacc[nt], 0, 0, 0);
  }

  // ---- coalesced O store through LDS (stride 80 shorts)
  __syncthreads();
#pragma unroll
  for (int nt = 0; nt < 4; ++nt)
#pragma unroll
    for (int r = 0; r < 4; ++r) {
      int row = wv * 16 + quad * 4 + r;
      P_lds[row * 80 + nt * 16 + lanelo] = f2bf(oacc[nt][r]);
    }
  __syncthreads();
#pragma unroll
  for (int rp = 0; rp < 64; rp += 32) {
    int row = rp + tid / 8, seg = tid % 8;
    short8 vv = *(const short8*)&P_lds[row * 80 + seg * 8];
    *(short8*)&attnb[(size_t)(l0 + row) * EMBED + h * 64 + seg * 8] = vv;
  }
}

extern "C" void kernel_launch(void* const* d_in, const int* in_sizes, int n_in,
                              void* d_out, int out_size, void* d_ws, size_t ws_size,
                              hipStream_t stream) {
  const float* x     = (const float*)d_in[0];   // [2048, 768]
  const float* w_qkv = (const float*)d_in[1];   // [768, 2304]
  const float* w_out = (const float*)d_in[2];   // [768, 768]
  const float* b_out = (const float*)d_in[3];   // [768]
  float* out = (float*)d_out;                   // [2048, 768]

  short *xb, *wqkvT, *woutT, *qkvb, *vT, *attnb;
  (void)hipGetSymbolAddress((void**)&xb,    HIP_SYMBOL(g_xb));
  (void)hipGetSymbolAddress((void**)&wqkvT, HIP_SYMBOL(g_wqkvT));
  (void)hipGetSymbolAddress((void**)&woutT, HIP_SYMBOL(g_woutT));
  (void)hipGetSymbolAddress((void**)&qkvb,  HIP_SYMBOL(g_qkvb));
  (void)hipGetSymbolAddress((void**)&vT,    HIP_SYMBOL(g_vT));
  (void)hipGetSymbolAddress((void**)&attnb, HIP_SYMBOL(g_attnb));

  // 1) fused prep (x cast, both weight transposes, vT pad zero)
  prep<<<PREP_TOT, 256, 0, stream>>>(x, w_qkv, w_out, xb, wqkvT, woutT, vT);

  // 2) qkv = x @ w_qkv -> bf16, fused V^T scatter. 1152 blocks, LDS-free K-loop.
  gemm_reg64<true, true><<<dim3(QKV_N / 64, LSEQ / 64), 256, 0, stream>>>(
      xb, wqkvT, nullptr, qkvb, vT, LSEQ, QKV_N, EMBED);

  // 3) windowed attention -> attnb (bf16). 384 blocks.
  attn_mfma<<<(LSEQ / 64) * HEADS, 256, 0, stream>>>(qkvb, vT, attnb);

  // 4) out = attn @ w_out + b_out (fp32). 384 blocks, LDS-free K-loop.
  gemm_reg64<false, false><<<dim3(EMBED / 64, LSEQ / 64), 256, 0, stream>>>(
      attnb, woutT, b_out, out, nullptr, LSEQ, EMBED, EMBED);
}

// Round 17
// 110.619 us; speedup vs baseline: 1.4626x; 1.4626x over previous
//
#include <hip/hip_runtime.h>
#include <hip/hip_bf16.h>

#define HEADS 12
#define HD 64
#define PADW 32
#define EMBED 768
#define LSEQ 2048
#define QKV_N (3 * HEADS * HD)   // 2304
#define LPAD (LSEQ + 64)         // 2112

typedef short short8 __attribute__((ext_vector_type(8)));
typedef short short4v __attribute__((ext_vector_type(4)));
typedef float f32x4 __attribute__((ext_vector_type(4)));

// Static scratch, fully overwritten every call (poison-safe).
__device__ short g_xb[LSEQ * EMBED];        // x bf16             [2048][768]
__device__ short g_wqkvT[QKV_N * EMBED];    // w_qkv^T bf16       [2304][768]
__device__ short g_woutT[EMBED * EMBED];    // w_out^T bf16       [768][768]
__device__ short g_qkvb[LSEQ * QKV_N];      // qkv bf16           [2048][2304]
__device__ short g_vT[HEADS * HD * LPAD];   // V^T bf16, 0-padded [768][2112]
__device__ short g_attnb[LSEQ * EMBED];     // attn out bf16      [2048][768]

__device__ __forceinline__ short f2bf(float f) {
  unsigned x = __builtin_bit_cast(unsigned, f);
  x += 0x7fffu + ((x >> 16) & 1u);   // RNE
  return (short)(x >> 16);
}

#define GLB(p) ((const __attribute__((address_space(1))) void*)(p))
#define LDS(p) ((__attribute__((address_space(3))) void*)(p))

// ---------------------------------------------------------------------------
// prep (unchanged, verified): A = cast x, B = w_qkv transpose, C = w_out
// transpose, D = zero vT pads. One dispatch, 3864 blocks.
// ---------------------------------------------------------------------------
#define PREP_A 1536              // (2048*768/4)/256
#define PREP_B 1728              // w_qkv: 72 x 24 tiles of 32x32
#define PREP_C 576               // w_out: 24 x 24
#define PREP_D 24                // vT pad zero
#define PREP_TOT (PREP_A + PREP_B + PREP_C + PREP_D)

__global__ __launch_bounds__(256) void prep(
    const float* __restrict__ x, const float* __restrict__ w_qkv,
    const float* __restrict__ w_out, short* __restrict__ xb,
    short* __restrict__ wqkvT, short* __restrict__ woutT,
    short* __restrict__ vT) {
  __shared__ float T[32][33];
  const int b = blockIdx.x, tid = threadIdx.x;
  if (b < PREP_A) {
    int i = b * 256 + tid;
    float4 v = ((const float4*)x)[i];
    short4v o;
    o[0] = f2bf(v.x); o[1] = f2bf(v.y); o[2] = f2bf(v.z); o[3] = f2bf(v.w);
    ((short4v*)xb)[i] = o;
  } else if (b < PREP_A + PREP_B + PREP_C) {
    const float* W; short* WT; int N, bx, by;
    if (b < PREP_A + PREP_B) {
      int t = b - PREP_A; W = w_qkv; WT = wqkvT; N = QKV_N; bx = t % 72; by = t / 72;
    } else {
      int t = b - PREP_A - PREP_B; W = w_out; WT = woutT; N = EMBED; bx = t % 24; by = t / 24;
    }
    const int K = EMBED;
    int tx = tid & 31, ty = tid >> 5;
    int n0 = bx * 32, k0 = by * 32;
#pragma unroll
    for (int p = 0; p < 4; ++p)
      T[ty + p * 8][tx] = W[(size_t)(k0 + ty + p * 8) * N + n0 + tx];
    __syncthreads();
#pragma unroll
    for (int p = 0; p < 4; ++p)
      WT[(size_t)(n0 + ty + p * 8) * K + k0 + tx] = f2bf(T[tx][ty + p * 8]);
  } else {
    int j = (b - PREP_A - PREP_B - PREP_C) * 256 + tid;
    int hd = j >> 3, side = (j >> 2) & 1, off = (j & 3) * 8;
    short8 z = {};
    *(short8*)&vT[(size_t)hd * LPAD + side * 2080 + off] = z;
  }
}

// ---------------------------------------------------------------------------
// ROUND 17: REVERT to r12 (verified 110.8us) — wave-private barrier-free
// GEMM pipeline. H5 (LDS-free K-loop) is ABANDONED: r14 (struct/lambda)
// and r16 (named-locals macro) both compiled to VGPR_Count 32/44 — the
// compiler SINKS plain global loads to first use to minimize register
// pressure, serializing the pipeline (issue 8 loads -> full-latency wait
// -> 8 MFMA, x12) -> 59us/gemm. There is no HIP-source mechanism to pin
// loads early without forcing a wait; global_load_lds is the only async
// staging path whose issue point the compiler preserves (no dest register
// to sink). This kernel: each wave owns a private 32x32 output tile +
// private 2x8KB LDS buffers, loads exactly the A/B rows it consumes,
// paces itself only by its own vmcnt. ZERO block-wide barriers.
// WAR without barriers: ds_reads of buf j drained by lgkmcnt(0) BEFORE
// stage(j+2) is issued into the same buffer (single-wave program order).
// vmcnt ledger: 8 loads/stage; steady wait vmcnt(8); final vmcnt(0).
// ---------------------------------------------------------------------------
template <bool OUT_BF16, bool FUSE_VT>
__global__ __launch_bounds__(256) void gemm_wp64(
    const short* __restrict__ A, const short* __restrict__ Bt,
    const float* __restrict__ bias, void* __restrict__ Cv,
    short* __restrict__ vT, int M, int N, int K) {
  // 4 waves x 2 buffers x (A 32x64 + B 32x64) shorts = 65536 B total.
  __shared__ __align__(16) short lds_s[4 * 2 * 4096];

  const int tid = threadIdx.x;
  const int wv = tid >> 6, lane = tid & 63;
  const int wm = wv >> 1, wn = wv & 1;
  const int lanelo = lane & 15, quad = lane >> 4;
  const int m0 = blockIdx.y * 64 + wm * 32;      // wave-owned 32 rows
  const int n0 = blockIdx.x * 64 + wn * 32;      // wave-owned 32 cols
  const int srow8 = lane >> 3, schk = lane & 7;  // 8 rows x 8 16B chunks
  const int sgc = schk ^ srow8;                  // swizzled global chunk
  const int xk = lanelo & 7;                     // read-side XOR key
  short* wlds = lds_s + wv * 2 * 4096;           // wave-private 16KB

  f32x4 acc[2][2] = {};

  auto stage = [&](int j, int buf) {
    short* Ab = wlds + buf * 4096;               // A: 2048 shorts
    short* Bb = Ab + 2048;                       // B: 2048 shorts
    const int k0 = j * 64;
#pragma unroll
    for (int c = 0; c < 4; ++c) {                // 8 rows per pass
      int row = c * 8 + srow8;
      const short* ga = A + (size_t)(m0 + row) * K + k0 + sgc * 8;
      __builtin_amdgcn_global_load_lds(GLB(ga), LDS(&Ab[c * 8 * 64]), 16, 0, 0);
    }
#pragma unroll
    for (int c = 0; c < 4; ++c) {
      int row = c * 8 + srow8;
      const short* gb = Bt + (size_t)(n0 + row) * K + k0 + sgc * 8;
      __builtin_amdgcn_global_load_lds(GLB(gb), LDS(&Bb[c * 8 * 64]), 16, 0, 0);
    }
  };

  const int steps = K / 64;                      // 12
  stage(0, 0);
  stage(1, 1);
  for (int j = 0; j < steps; ++j) {
    const int buf = j & 1;
    if (j < steps - 1) asm volatile("s_waitcnt vmcnt(8)" ::: "memory");
    else               asm volatile("s_waitcnt vmcnt(0)" ::: "memory");
    short* Ab = wlds + buf * 4096;
    short* Bb = Ab + 2048;
    short8 af[2][2], bfr[2][2];                  // [ks][mt/nt]
#pragma unroll
    for (int ks = 0; ks < 2; ++ks) {
      int p = (ks * 4 + quad) ^ xk;              // physical chunk
#pragma unroll
      for (int mt = 0; mt < 2; ++mt)
        af[ks][mt] = *(const short8*)&Ab[(mt * 16 + lanelo) * 64 + p * 8];
#pragma unroll
      for (int nt = 0; nt < 2; ++nt)
        bfr[ks][nt] = *(const short8*)&Bb[(nt * 16 + lanelo) * 64 + p * 8];
    }
    asm volatile("s_waitcnt lgkmcnt(0)" ::: "memory");   // frags in regs
    if (j + 2 < steps) stage(j + 2, buf);        // overwrite now-drained buf
#pragma unroll
    for (int ks = 0; ks < 2; ++ks)
#pragma unroll
      for (int mt = 0; mt < 2; ++mt)
#pragma unroll
        for (int nt = 0; nt < 2; ++nt)
          acc[mt][nt] = __builtin_amdgcn_mfma_f32_16x16x32_bf16(
              af[ks][mt], bfr[ks][nt], acc[mt][nt], 0, 0, 0);
  }

  // ---- fused V^T scatter: any 16-col group with c0 % 192 >= 128 is V ----
  if (FUSE_VT) {
#pragma unroll
    for (int nt = 0; nt < 2; ++nt) {
      int c0 = n0 + nt * 16;                     // wave-uniform
      if ((c0 % 192) >= 128) {
        int h = c0 / 192, d0 = (c0 % 192) - 128;
#pragma unroll
        for (int mt = 0; mt < 2; ++mt) {
          int d = d0 + lanelo;
          int row0 = m0 + mt * 16 + quad * 4;
          short4v o;
#pragma unroll
          for (int r = 0; r < 4; ++r) o[r] = f2bf(acc[mt][nt][r]);
          *(short4v*)&vT[(size_t)(h * 64 + d) * LPAD + PADW + row0] = o;
        }
      }
    }
  }

  // ---- wave-private coalesced epilogue (no __syncthreads anywhere) ----
  if (OUT_BF16) {
    constexpr int ST = 40;                       // 32 + 8 pad shorts
    short* eb = wlds;                            // K-loop buffers dead
#pragma unroll
    for (int mt = 0; mt < 2; ++mt)
#pragma unroll
      for (int nt = 0; nt < 2; ++nt) {
        int rloc = mt * 16 + quad * 4;
        int cloc = nt * 16 + lanelo;
#pragma unroll
        for (int r = 0; r < 4; ++r)
          eb[(rloc + r) * ST + cloc] = f2bf(acc[mt][nt][r]);
      }
    asm volatile("s_waitcnt lgkmcnt(0)" ::: "memory");
    short* Cc = (short*)Cv;
#pragma unroll
    for (int pass = 0; pass < 2; ++pass) {
      int u = pass * 64 + lane;
      int row = u >> 2, seg = u & 3;             // 32 rows x 4 x short8
      short8 vv = *(const short8*)&eb[row * ST + seg * 8];
      *(short8*)&Cc[(size_t)(m0 + row) * N + n0 + seg * 8] = vv;
    }
  } else {
    constexpr int ST = 36;                       // 32 + 4 pad floats
    float* fl = (float*)wlds;
#pragma unroll
    for (int mt = 0; mt < 2; ++mt)
#pragma unroll
      for (int nt = 0; nt < 2; ++nt) {
        int rloc = mt * 16 + quad * 4;
        int cloc = nt * 16 + lanelo;
#pragma unroll
        for (int r = 0; r < 4; ++r)
          fl[(rloc + r) * ST + cloc] = acc[mt][nt][r];
      }
    asm volatile("s_waitcnt lgkmcnt(0)" ::: "memory");
    float* Cc = (float*)Cv;
#pragma unroll
    for (int pass = 0; pass < 4; ++pass) {
      int u = pass * 64 + lane;
      int row = u >> 3, seg = u & 7;             // 32 rows x 8 x float4
      float4 vv = *(const float4*)&fl[row * ST + seg * 4];
      float4 bb = *(const float4*)&bias[n0 + seg * 4];
      vv.x += bb.x; vv.y += bb.y; vv.z += bb.z; vv.w += bb.w;
      *(float4*)&Cc[(size_t)(m0 + row) * N + n0 + seg * 4] = vv;
    }
  }
}

// ---------------------------------------------------------------------------
// MFMA windowed attention (unchanged, verified). Block = 64 rows x 1 head;
// 4 waves, 16-row strips; V b-frags prefetched before the softmax phase.
// ---------------------------------------------------------------------------
__global__ __launch_bounds__(256) void attn_mfma(
    const short* __restrict__ qkvb, const short* __restrict__ vT,
    short* __restrict__ attnb) {
  const int blk = blockIdx.x;
  const int h = blk % HEADS;
  const int l0 = (blk / HEADS) * 64;
  const int sb = l0 - PADW;

  const int tid = threadIdx.x;
  const int wv = tid >> 6, lane = tid & 63;
  const int lanelo = lane & 15, quad = lane >> 4;
  const int qoff = h * 192, koff = h * 192 + 64;

  __shared__ __align__(16) short P_lds[64 * 136];

  // Q a-frags
  const short* qp = qkvb + (size_t)(l0 + wv * 16 + lanelo) * QKV_N + qoff;
  short8 aq0 = *(const short8*)(qp + quad * 8);
  short8 aq1 = *(const short8*)(qp + 32 + quad * 8);

  // ---- S = Q.K^T
  f32x4 sacc[8] = {};
#pragma unroll
  for (int nt = 0; nt < 8; ++nt) {
    int gl = sb + nt * 16 + lanelo;
    short8 bk0 = {}, bk1 = {};
    if ((unsigned)gl < (unsigned)LSEQ) {
      const short* kp = qkvb + (size_t)gl * QKV_N + koff;
      bk0 = *(const short8*)(kp + quad * 8);
      bk1 = *(const short8*)(kp + 32 + quad * 8);
    }
    sacc[nt] = __builtin_amdgcn_mfma_f32_16x16x32_bf16(aq0, bk0, sacc[nt], 0, 0, 0);
    sacc[nt] = __builtin_amdgcn_mfma_f32_16x16x32_bf16(aq1, bk1, sacc[nt], 0, 0, 0);
  }

  // ---- V b-frag prefetch (independent of softmax)
  short8 bv[4][4];
#pragma unroll
  for (int ks = 0; ks < 4; ++ks) {
    int lp = l0 + ks * 32 + quad * 8;
#pragma unroll
    for (int nt = 0; nt < 4; ++nt) {
      int d = nt * 16 + lanelo;
      bv[ks][nt] = *(const short8*)&vT[((size_t)h * 64 + d) * LPAD + lp];
    }
  }

  // ---- softmax per row (no max-pass; masked -> exp(-1e30) == 0)
  float rsum[4] = {0.f, 0.f, 0.f, 0.f};
#pragma unroll
  for (int nt = 0; nt < 8; ++nt)
#pragma unroll
    for (int r = 0; r < 4; ++r) {
      int li = wv * 16 + quad * 4 + r;
      int widx = nt * 16 + lanelo - li;
      float s = (widx >= 0 && widx <= 64) ? sacc[nt][r] * 0.125f : -1e30f;
      float p = __expf(s);
      sacc[nt][r] = p;
      rsum[r] += p;
    }
#pragma unroll
  for (int r = 0; r < 4; ++r) {
#pragma unroll
    for (int off = 1; off < 16; off <<= 1)
      rsum[r] += __shfl_xor(rsum[r], off);
    rsum[r] = 1.f / rsum[r];
  }
#pragma unroll
  for (int nt = 0; nt < 8; ++nt)
#pragma unroll
    for (int r = 0; r < 4; ++r) {
      int row = wv * 16 + quad * 4 + r;
      P_lds[row * 136 + nt * 16 + lanelo] = f2bf(sacc[nt][r] * rsum[r]);
    }
  __syncthreads();

  // ---- O = P.V (V already in regs)
  f32x4 oacc[4] = {};
#pragma unroll
  for (int ks = 0; ks < 4; ++ks) {
    short8 ap = *(const short8*)&P_lds[(wv * 16 + lanelo) * 136 + ks * 32 + quad * 8];
#pragma unroll
    for (int nt = 0; nt < 4; ++nt)
      oacc[nt] = __builtin_amdgcn_mfma_f32_16x16x32_bf16(ap, bv[ks][nt], oacc[nt], 0, 0, 0);
  }

  // ---- coalesced O store through LDS (stride 80 shorts)
  __syncthreads();
#pragma unroll
  for (int nt = 0; nt < 4; ++nt)
#pragma unroll
    for (int r = 0; r < 4; ++r) {
      int row = wv * 16 + quad * 4 + r;
      P_lds[row * 80 + nt * 16 + lanelo] = f2bf(oacc[nt][r]);
    }
  __syncthreads();
#pragma unroll
  for (int rp = 0; rp < 64; rp += 32) {
    int row = rp + tid / 8, seg = tid % 8;
    short8 vv = *(const short8*)&P_lds[row * 80 + seg * 8];
    *(short8*)&attnb[(size_t)(l0 + row) * EMBED + h * 64 + seg * 8] = vv;
  }
}

extern "C" void kernel_launch(void* const* d_in, const int* in_sizes, int n_in,
                              void* d_out, int out_size, void* d_ws, size_t ws_size,
                              hipStream_t stream) {
  const float* x     = (const float*)d_in[0];   // [2048, 768]
  const float* w_qkv = (const float*)d_in[1];   // [768, 2304]
  const float* w_out = (const float*)d_in[2];   // [768, 768]
  const float* b_out = (const float*)d_in[3];   // [768]
  float* out = (float*)d_out;                   // [2048, 768]

  short *xb, *wqkvT, *woutT, *qkvb, *vT, *attnb;
  (void)hipGetSymbolAddress((void**)&xb,    HIP_SYMBOL(g_xb));
  (void)hipGetSymbolAddress((void**)&wqkvT, HIP_SYMBOL(g_wqkvT));
  (void)hipGetSymbolAddress((void**)&woutT, HIP_SYMBOL(g_woutT));
  (void)hipGetSymbolAddress((void**)&qkvb,  HIP_SYMBOL(g_qkvb));
  (void)hipGetSymbolAddress((void**)&vT,    HIP_SYMBOL(g_vT));
  (void)hipGetSymbolAddress((void**)&attnb, HIP_SYMBOL(g_attnb));

  // 1) fused prep (x cast, both weight transposes, vT pad zero)
  prep<<<PREP_TOT, 256, 0, stream>>>(x, w_qkv, w_out, xb, wqkvT, woutT, vT);

  // 2) qkv = x @ w_qkv -> bf16, fused V^T scatter. 1152 blocks, barrier-free.
  gemm_wp64<true, true><<<dim3(QKV_N / 64, LSEQ / 64), 256, 0, stream>>>(
      xb, wqkvT, nullptr, qkvb, vT, LSEQ, QKV_N, EMBED);

  // 3) windowed attention -> attnb (bf16). 384 blocks.
  attn_mfma<<<(LSEQ / 64) * HEADS, 256, 0, stream>>>(qkvb, vT, attnb);

  // 4) out = attn @ w_out + b_out (fp32). 384 blocks, barrier-free.
  gemm_wp64<false, false><<<dim3(EMBED / 64, LSEQ / 64), 256, 0, stream>>>(
      attnb, woutT, b_out, out, nullptr, LSEQ, EMBED, EMBED);
}